// Round 7
// baseline (181.700 us; speedup 1.0000x reference)
//
#include <hip/hip_runtime.h>
#include <math.h>

constexpr int B_   = 4096;
constexpr int C_   = 100;
constexpr int D_   = 128;
constexpr int TWOB = 8192;
constexpr int NJ   = 8292;
constexpr int NJP  = 8320;          // padded cols (260 tiles of 32)
constexpr float LOG2E10 = 14.4269504089f;   // 10 * log2(e)

typedef __attribute__((ext_vector_type(8))) short short8;
typedef __attribute__((ext_vector_type(4))) float f32x4;

// ---------------- ws layout (bytes) ----------------
// 0       : int    cnt[128]            512
// 512     : float  Eacc[8192]        32768  -> 33280
// 33280   : float  G[100*128]        51200  -> 84480   (class feature sums; memset 0..84480)
// 84480   : int    tgtAll[8320]      33280  -> 117760
// 117760  : float4 tbl[8320]        133120  -> 250880  (.x=jt bits, .y=r0, .z=r1)
// 250880  : ushort fbB[8320*128]   2129920  -> 2380800 (unscaled bf16)
// 2380800 : ushort fbA[8192*128]   2097152  -> 4477952 (bf16 of feat*14.4269504)

__device__ __forceinline__ const float* feat_row(const float* __restrict__ centers,
                                                 const float* __restrict__ features,
                                                 int idx) {
  if (idx < B_)   return features + (size_t)idx * (2 * D_);
  if (idx < TWOB) return features + (size_t)(idx - B_) * (2 * D_) + D_;
  return centers + (size_t)(idx - TWOB) * D_;
}

__device__ __forceinline__ unsigned short f2bf(float x) {
  unsigned int u = __float_as_uint(x);
  unsigned int r = (u + 0x7FFFu + ((u >> 16) & 1u)) >> 16;   // RNE
  return (unsigned short)r;
}

__device__ __forceinline__ float bf2f(short s) {
  return __uint_as_float(((unsigned int)(unsigned short)s) << 16);
}

// targets table + class counts (counts over view-0 targets only; bcc = 2*cnt+1)
__global__ __launch_bounds__(256)
void tgt_count_kernel(const int* __restrict__ targets, int* __restrict__ cnt,
                      int* __restrict__ tgtAll) {
  int i = blockIdx.x * 256 + threadIdx.x;
  if (i >= NJP) return;
  int jt = (i < B_) ? targets[i]
         : (i < TWOB ? targets[i - B_] : (i < NJ ? i - TWOB : -9));
  tgtAll[i] = jt;
  if (i < B_) atomicAdd(&cnt[jt], 1);
}

// bf16 conversions + per-column tables (no G atomics here anymore)
__global__ __launch_bounds__(256)
void prep_kernel(const float* __restrict__ centers, const float* __restrict__ features,
                 const int* __restrict__ tgtAll, const int* __restrict__ cnt,
                 unsigned short* __restrict__ fbB, unsigned short* __restrict__ fbA,
                 float4* __restrict__ tbl) {
  int gidx = blockIdx.x * 256 + threadIdx.x;      // NJP*32 items
  if (gidx >= NJP * 32) return;
  int row = gidx >> 5;
  int q   = gidx & 31;                            // float4 index within row
  float4 v = make_float4(0.f, 0.f, 0.f, 0.f);
  if (row < NJ) v = *(const float4*)(feat_row(centers, features, row) + q * 4);
  ushort4 o;
  o.x = f2bf(v.x); o.y = f2bf(v.y); o.z = f2bf(v.z); o.w = f2bf(v.w);
  *(ushort4*)&fbB[(size_t)row * 128 + q * 4] = o;
  if (row < TWOB) {
    ushort4 a;
    a.x = f2bf(v.x * LOG2E10); a.y = f2bf(v.y * LOG2E10);
    a.z = f2bf(v.z * LOG2E10); a.w = f2bf(v.w * LOG2E10);
    *(ushort4*)&fbA[(size_t)row * 128 + q * 4] = a;
  }
  if (q == 0) {
    int jt = tgtAll[row];
    float r0 = 0.f, r1 = 0.f;
    if (jt >= 0) {
      float b = (float)(2 * cnt[jt] + 1);
      r0 = 1.f / b;
      r1 = 1.f / (b - 1.f);
    }
    tbl[row] = make_float4(__int_as_float(jt), r0, r1, 0.f);
  }
}

// class feature sums: one (class, row-chunk) block; uniform branch per row;
// one 128-wide atomic flush per block (51K atomics total vs 4.26M before).
__global__ __launch_bounds__(128)
void gsum_kernel(const float* __restrict__ centers, const float* __restrict__ features,
                 const int* __restrict__ tgtAll, float* __restrict__ G) {
  const int c     = blockIdx.x;          // class 0..99
  const int chunk = blockIdx.y;          // 0..7
  const int d     = threadIdx.x;         // dim 0..127
  int r0 = chunk * 1037;
  int r1 = r0 + 1037; if (r1 > NJ) r1 = NJ;
  float acc = 0.f;
  for (int r = r0; r < r1; ++r) {
    if (tgtAll[r] == c) {                // uniform across the block
      float v = feat_row(centers, features, r)[d];
      acc += bf2f((short)f2bf(v));       // bf16-rounded to match MFMA inputs
    }
  }
  if (acc != 0.f) atomicAdd(&G[c * 128 + d], acc);
}

// Wave-independent 64x32 MFMA tiles, no LDS, no barriers.
// Grid 512 blocks: id = strip(16) + 16*isuper(32); id%8 = strip%8 -> 2 strips/XCD.
// waves_per_eu(2,2): pin exactly 2 waves/SIMD -> up to 256 VGPR/wave, no spills.
__global__ __launch_bounds__(256) __attribute__((amdgpu_waves_per_eu(2, 2)))
void bal_mfma(const unsigned short* __restrict__ fbA, const unsigned short* __restrict__ fbB,
              const float4* __restrict__ tbl, float* __restrict__ Eacc) {
  const int t     = threadIdx.x;
  const int lane  = t & 63;
  const int w     = t >> 6;
  const int id    = blockIdx.x;
  const int strip = id & 15;
  const int isup  = id >> 4;
  const int rbase = isup * 256 + w * 64;
  const int lr    = lane & 15;
  const int lh    = lane >> 4;

  const int jg0 = strip * 16 + (strip < 4 ? strip : 4);
  const int jg1 = jg0 + 16 + (strip < 4 ? 1 : 0);     // 260 tiles of 32 cols

  // ---- A fragments (scaled copy), held for the whole strip ----
  short8 af[4][4];                  // [ks][m]
  #pragma unroll
  for (int ks = 0; ks < 4; ++ks)
    #pragma unroll
    for (int m = 0; m < 4; ++m)
      af[ks][m] = *(const short8*)&fbA[(size_t)(rbase + m * 16 + lr) * 128 + (ks * 4 + lh) * 8];

  int ti[4][4];
  #pragma unroll
  for (int m = 0; m < 4; ++m)
    #pragma unroll
    for (int g = 0; g < 4; ++g)
      ti[m][g] = __float_as_int(tbl[rbase + m * 16 + lh * 4 + g].x);

  float ep[4][4];
  #pragma unroll
  for (int m = 0; m < 4; ++m)
    #pragma unroll
    for (int g = 0; g < 4; ++g) ep[m][g] = 0.f;

  short8 b0[2][4], b1[2][4];        // [n][ks]
  float4 t0[2], t1[2];

  auto loadB = [&](int jg, short8 (&b)[2][4], float4 (&tb)[2]) {
    int jb = jg * 32;
    #pragma unroll
    for (int n = 0; n < 2; ++n) {
      tb[n] = tbl[jb + n * 16 + lr];
      #pragma unroll
      for (int ks = 0; ks < 4; ++ks)
        b[n][ks] = *(const short8*)&fbB[(size_t)(jb + n * 16 + lr) * 128 + (ks * 4 + lh) * 8];
    }
  };

  auto compute = [&](short8 (&b)[2][4], float4 (&tb)[2]) {
    f32x4 acc[4][2];
    #pragma unroll
    for (int m = 0; m < 4; ++m)
      #pragma unroll
      for (int n = 0; n < 2; ++n) acc[m][n] = (f32x4){0.f, 0.f, 0.f, 0.f};
    #pragma unroll
    for (int ks = 0; ks < 4; ++ks)
      #pragma unroll
      for (int n = 0; n < 2; ++n)
        #pragma unroll
        for (int m = 0; m < 4; ++m)
          acc[m][n] = __builtin_amdgcn_mfma_f32_16x16x32_bf16(af[ks][m], b[n][ks], acc[m][n], 0, 0, 0);
    #pragma unroll
    for (int n = 0; n < 2; ++n) {
      int   jtn = __float_as_int(tb[n].x);
      float r0  = tb[n].y, r1 = tb[n].z;
      #pragma unroll
      for (int m = 0; m < 4; ++m)
        #pragma unroll
        for (int g = 0; g < 4; ++g) {
          float e = __builtin_amdgcn_exp2f(acc[m][n][g]);   // exp(10*dot)
          ep[m][g] = fmaf(e, (ti[m][g] == jtn) ? r1 : r0, ep[m][g]);
        }
    }
  };

  // ---- ping-pong over the strip ----
  int jg = jg0;
  loadB(jg0, b0, t0);
  while (jg + 2 <= jg1) {
    loadB(jg + 1, b1, t1);
    compute(b0, t0);
    if (jg + 2 < jg1) loadB(jg + 2, b0, t0);
    compute(b1, t1);
    jg += 2;
  }
  if (jg < jg1) compute(b0, t0);

  // ---- reduce over the 16 column-lanes, atomic per row ----
  #pragma unroll
  for (int mk = 1; mk <= 8; mk <<= 1)
    #pragma unroll
    for (int m = 0; m < 4; ++m)
      #pragma unroll
      for (int g = 0; g < 4; ++g)
        ep[m][g] += __shfl_xor(ep[m][g], mk, 64);
  if (lr == 0) {
    #pragma unroll
    for (int m = 0; m < 4; ++m)
      #pragma unroll
      for (int g = 0; g < 4; ++g)
        atomicAdd(&Eacc[rbase + m * 16 + lh * 4 + g], ep[m][g]);
  }
}

// Per-row finish: diag subtraction (exact MFMA-matching self-dot) + analytic
// positive-sum via class sums G, then mean.
__global__ __launch_bounds__(256)
void bal_final(const unsigned short* __restrict__ fbA, const unsigned short* __restrict__ fbB,
               const float4* __restrict__ tbl, const float* __restrict__ G,
               const float* __restrict__ Eacc, float* __restrict__ out) {
  int t    = threadIdx.x;
  int row  = blockIdx.x * 64 + (t >> 2);       // 128 blocks x 64 rows
  int part = t & 3;                             // 32 dims per lane-part
  const unsigned short* pa = fbA + (size_t)row * 128 + part * 32;
  const unsigned short* pb = fbB + (size_t)row * 128 + part * 32;
  float4 tb = tbl[row];
  int   ti  = __float_as_int(tb.x);
  const float* gp = G + ti * 128 + part * 32;

  float sA = 0.f, sB = 0.f, sG = 0.f;
  #pragma unroll
  for (int q = 0; q < 4; ++q) {
    short8 va = *(const short8*)&pa[q * 8];
    short8 vb = *(const short8*)&pb[q * 8];
    #pragma unroll
    for (int d = 0; d < 8; ++d) {
      float fa = bf2f(va[d]);
      float fb = bf2f(vb[d]);
      float gv = gp[q * 8 + d];
      sA = fmaf(fa, fb, sA);    // scaled self-dot, matches MFMA diag acc
      sB = fmaf(fb, fb, sB);    // unscaled self-dot
      sG = fmaf(fb, gv, sG);    // dot with class sum
    }
  }
  sA += __shfl_xor(sA, 1, 64); sA += __shfl_xor(sA, 2, 64);
  sB += __shfl_xor(sB, 1, 64); sB += __shfl_xor(sB, 2, 64);
  sG += __shfl_xor(sG, 1, 64); sG += __shfl_xor(sG, 2, 64);

  float r1 = tb.z;                               // 1/(2*cnt[ti])
  float ep = Eacc[row] - __builtin_amdgcn_exp2f(sA) * r1;
  float ma = 10.f * (sG - sB);                   // sum of mask*logit
  float li = ma * r1 - logf(ep);
  // each row has 4 identical lane-copies -> pre-scale by 1/4; full-wave
  // butterfly then leaves the exact wave total in every lane.
  float local = -li * (1.f / (8192.f * 4.f));

  #pragma unroll
  for (int mk = 1; mk < 64; mk <<= 1) local += __shfl_xor(local, mk, 64);
  if ((t & 63) == 0) atomicAdd(out, local);
}

extern "C" void kernel_launch(void* const* d_in, const int* in_sizes, int n_in,
                              void* d_out, int out_size, void* d_ws, size_t ws_size,
                              hipStream_t stream) {
  const float* centers  = (const float*)d_in[0];
  const float* features = (const float*)d_in[1];
  const int*   targets  = (const int*)d_in[2];

  char* ws = (char*)d_ws;
  int*            cnt    = (int*)ws;
  float*          Eacc   = (float*)(ws + 512);
  float*          G      = (float*)(ws + 33280);
  int*            tgtAll = (int*)(ws + 84480);
  float4*         tbl    = (float4*)(ws + 117760);
  unsigned short* fbB    = (unsigned short*)(ws + 250880);
  unsigned short* fbA    = (unsigned short*)(ws + 2380800);
  float* out = (float*)d_out;

  hipMemsetAsync(ws, 0, 84480, stream);          // cnt + Eacc + G
  hipMemsetAsync(d_out, 0, sizeof(float), stream);
  tgt_count_kernel<<<(NJP + 255) / 256, 256, 0, stream>>>(targets, cnt, tgtAll);
  prep_kernel<<<(NJP * 32 + 255) / 256, 256, 0, stream>>>(centers, features, tgtAll, cnt,
                                                          fbB, fbA, tbl);
  gsum_kernel<<<dim3(C_, 8), 128, 0, stream>>>(centers, features, tgtAll, G);
  bal_mfma<<<512, 256, 0, stream>>>(fbA, fbB, tbl, Eacc);
  bal_final<<<TWOB / 64, 256, 0, stream>>>(fbA, fbB, tbl, G, Eacc, out);
}

// Round 8
// 120.553 us; speedup vs baseline: 1.5072x; 1.5072x over previous
//
#include <hip/hip_runtime.h>
#include <math.h>

constexpr int B_   = 4096;
constexpr int C_   = 100;
constexpr int D_   = 128;
constexpr int TWOB = 8192;
constexpr int NJ   = 8292;
constexpr int NJP  = 8320;          // padded cols (520 quanta of 16)
constexpr float LOG2E10 = 14.4269504089f;   // 10 * log2(e)
constexpr float LN2     = 0.6931471805599453f;

typedef __attribute__((ext_vector_type(8))) short short8;
typedef __attribute__((ext_vector_type(4))) float f32x4;

// ---------------- ws layout (bytes) ----------------
// 0       : int    cnt[128]            512
// 512     : float  Eacc[8192]        32768  -> 33280
// 33280   : float  Sacc[8192]        32768  -> 66048   (memset 0..66048)
// 66048   : int    tgtAll[8320]      33280  -> 99328
// 99328   : float4 tbl[8320]        133120  -> 232448  (.x=jt bits, .y=r0, .z=r1)
// 232448  : ushort fbB[8320*128]   2129920  -> 2362368 (unscaled bf16)
// 2362368 : ushort fbA[8192*128]   2097152  -> 4459520 (bf16 of feat*14.4269504)

__device__ __forceinline__ const float* feat_row(const float* __restrict__ centers,
                                                 const float* __restrict__ features,
                                                 int idx) {
  if (idx < B_)   return features + (size_t)idx * (2 * D_);
  if (idx < TWOB) return features + (size_t)(idx - B_) * (2 * D_) + D_;
  return centers + (size_t)(idx - TWOB) * D_;
}

__device__ __forceinline__ unsigned short f2bf(float x) {
  unsigned int u = __float_as_uint(x);
  unsigned int r = (u + 0x7FFFu + ((u >> 16) & 1u)) >> 16;   // RNE
  return (unsigned short)r;
}

__device__ __forceinline__ float bf2f(short s) {
  return __uint_as_float(((unsigned int)(unsigned short)s) << 16);
}

// targets table + class counts
__global__ __launch_bounds__(256)
void tgt_count_kernel(const int* __restrict__ targets, int* __restrict__ cnt,
                      int* __restrict__ tgtAll) {
  int i = blockIdx.x * 256 + threadIdx.x;
  if (i >= NJP) return;
  int jt = (i < B_) ? targets[i]
         : (i < TWOB ? targets[i - B_] : (i < NJ ? i - TWOB : -9));
  tgtAll[i] = jt;
  if (i < B_) atomicAdd(&cnt[jt], 1);
}

// bf16 conversions + per-column tables
__global__ __launch_bounds__(256)
void prep_kernel(const float* __restrict__ centers, const float* __restrict__ features,
                 const int* __restrict__ tgtAll, const int* __restrict__ cnt,
                 unsigned short* __restrict__ fbB, unsigned short* __restrict__ fbA,
                 float4* __restrict__ tbl) {
  int gidx = blockIdx.x * 256 + threadIdx.x;      // NJP*32 items
  if (gidx >= NJP * 32) return;
  int row = gidx >> 5;
  int q   = gidx & 31;                            // float4 index within row
  float4 v = make_float4(0.f, 0.f, 0.f, 0.f);
  if (row < NJ) v = *(const float4*)(feat_row(centers, features, row) + q * 4);
  ushort4 o;
  o.x = f2bf(v.x); o.y = f2bf(v.y); o.z = f2bf(v.z); o.w = f2bf(v.w);
  *(ushort4*)&fbB[(size_t)row * 128 + q * 4] = o;
  if (row < TWOB) {
    ushort4 a;
    a.x = f2bf(v.x * LOG2E10); a.y = f2bf(v.y * LOG2E10);
    a.z = f2bf(v.z * LOG2E10); a.w = f2bf(v.w * LOG2E10);
    *(ushort4*)&fbA[(size_t)row * 128 + q * 4] = a;
  }
  if (q == 0) {
    int jt = tgtAll[row];
    float r0 = 0.f, r1 = 0.f;
    if (jt >= 0) {
      float b = (float)(2 * cnt[jt] + 1);
      r0 = 1.f / b;
      r1 = 1.f / (b - 1.f);
    }
    tbl[row] = make_float4(__int_as_float(jt), r0, r1, 0.f);
  }
}

// Wave-independent 64-row x 16-col MFMA quanta, no LDS, no barriers.
// Grid 512 blocks: id = strip(16) + 16*isuper(32); id%8 = strip%8 -> 2 strips/XCD.
// waves_per_eu(2,2): exactly 2 waves/SIMD -> 256 VGPR budget, live set ~180.
__global__ __launch_bounds__(256) __attribute__((amdgpu_waves_per_eu(2, 2)))
void bal_mfma(const unsigned short* __restrict__ fbA, const unsigned short* __restrict__ fbB,
              const float4* __restrict__ tbl, float* __restrict__ Eacc,
              float* __restrict__ Sacc) {
  const int t     = threadIdx.x;
  const int lane  = t & 63;
  const int w     = t >> 6;
  const int id    = blockIdx.x;
  const int strip = id & 15;
  const int isup  = id >> 4;
  const int rbase = isup * 256 + w * 64;
  const int lr    = lane & 15;
  const int lh    = lane >> 4;

  // 520 quanta of 16 cols over 16 strips: strips 0..7 get 33, 8..15 get 32
  const int q0 = strip * 32 + (strip < 8 ? strip : 8);
  const int q1 = q0 + 32 + (strip < 8 ? 1 : 0);

  // ---- A fragments (scaled copy), held for the whole strip ----
  short8 af[4][4];                  // [ks][m]  = 64 VGPR
  #pragma unroll
  for (int ks = 0; ks < 4; ++ks)
    #pragma unroll
    for (int m = 0; m < 4; ++m)
      af[ks][m] = *(const short8*)&fbA[(size_t)(rbase + m * 16 + lr) * 128 + (ks * 4 + lh) * 8];

  int ti[4][4];
  #pragma unroll
  for (int m = 0; m < 4; ++m)
    #pragma unroll
    for (int g = 0; g < 4; ++g)
      ti[m][g] = __float_as_int(tbl[rbase + m * 16 + lh * 4 + g].x);

  float ep[4][4], ma[4][4];
  #pragma unroll
  for (int m = 0; m < 4; ++m)
    #pragma unroll
    for (int g = 0; g < 4; ++g) { ep[m][g] = 0.f; ma[m][g] = 0.f; }

  short8 bA[4], bB[4];              // [ks] for current/next quantum (32 VGPR)
  float4 tA, tB;

  auto loadQ = [&](int jq, short8 (&b)[4], float4& tb) {
    int jb = jq * 16;
    tb = tbl[jb + lr];
    #pragma unroll
    for (int ks = 0; ks < 4; ++ks)
      b[ks] = *(const short8*)&fbB[(size_t)(jb + lr) * 128 + (ks * 4 + lh) * 8];
  };

  auto computeQ = [&](short8 (&b)[4], float4& tb) {
    f32x4 acc[4];
    #pragma unroll
    for (int m = 0; m < 4; ++m) acc[m] = (f32x4){0.f, 0.f, 0.f, 0.f};
    #pragma unroll
    for (int ks = 0; ks < 4; ++ks)
      #pragma unroll
      for (int m = 0; m < 4; ++m)
        acc[m] = __builtin_amdgcn_mfma_f32_16x16x32_bf16(af[ks][m], b[ks], acc[m], 0, 0, 0);
    int   jtq = __float_as_int(tb.x);
    float r0q = tb.y, r1q = tb.z;
    #pragma unroll
    for (int m = 0; m < 4; ++m)
      #pragma unroll
      for (int g = 0; g < 4; ++g) {
        float a = acc[m][g];
        float e = __builtin_amdgcn_exp2f(a);    // exp(10*dot); diag handled in final
        bool eq = (ti[m][g] == jtq);
        ep[m][g] = fmaf(e, eq ? r1q : r0q, ep[m][g]);
        ma[m][g] += eq ? a : 0.f;
      }
  };

  // ---- ping-pong over the strip (16-col quanta) ----
  int jq = q0;
  loadQ(q0, bA, tA);
  while (jq + 2 <= q1) {
    loadQ(jq + 1, bB, tB);
    computeQ(bA, tA);
    if (jq + 2 < q1) loadQ(jq + 2, bA, tA);
    computeQ(bB, tB);
    jq += 2;
  }
  if (jq < q1) computeQ(bA, tA);

  // ---- reduce over the 16 column-lanes, atomics per row ----
  #pragma unroll
  for (int mk = 1; mk <= 8; mk <<= 1)
    #pragma unroll
    for (int m = 0; m < 4; ++m)
      #pragma unroll
      for (int g = 0; g < 4; ++g) {
        ep[m][g] += __shfl_xor(ep[m][g], mk, 64);
        ma[m][g] += __shfl_xor(ma[m][g], mk, 64);
      }
  if (lr == 0) {
    #pragma unroll
    for (int m = 0; m < 4; ++m)
      #pragma unroll
      for (int g = 0; g < 4; ++g) {
        int i = rbase + m * 16 + lh * 4 + g;
        atomicAdd(&Eacc[i], ep[m][g]);
        atomicAdd(&Sacc[i], ma[m][g]);
      }
  }
}

// Per-row finish: exact diag subtraction from both E and S, then mean.
__global__ __launch_bounds__(256)
void bal_final(const unsigned short* __restrict__ fbA, const unsigned short* __restrict__ fbB,
               const float4* __restrict__ tbl,
               const float* __restrict__ Eacc, const float* __restrict__ Sacc,
               float* __restrict__ out) {
  int t    = threadIdx.x;
  int row  = blockIdx.x * 64 + (t >> 2);       // 128 blocks x 64 rows
  int part = t & 3;                             // 32 dims per lane-part
  const unsigned short* pa = fbA + (size_t)row * 128 + part * 32;
  const unsigned short* pb = fbB + (size_t)row * 128 + part * 32;
  float4 tb = tbl[row];

  float sA = 0.f;                               // scaled self-dot (= MFMA diag acc)
  #pragma unroll
  for (int q = 0; q < 4; ++q) {
    short8 va = *(const short8*)&pa[q * 8];
    short8 vb = *(const short8*)&pb[q * 8];
    #pragma unroll
    for (int d = 0; d < 8; ++d)
      sA = fmaf(bf2f(va[d]), bf2f(vb[d]), sA);
  }
  sA += __shfl_xor(sA, 1, 64);
  sA += __shfl_xor(sA, 2, 64);

  float r1 = tb.z;                               // 1/(2*cnt[t_i])
  float ep = Eacc[row] - __builtin_amdgcn_exp2f(sA) * r1;
  float ma = LN2 * (Sacc[row] - sA);             // sum of mask*logit (diag removed)
  float li = ma * r1 - logf(ep);
  // each row has 4 identical lane-copies -> pre-scale by 1/4; full-wave
  // butterfly leaves the exact wave total in every lane.
  float local = -li * (1.f / (8192.f * 4.f));

  #pragma unroll
  for (int mk = 1; mk < 64; mk <<= 1) local += __shfl_xor(local, mk, 64);
  if ((t & 63) == 0) atomicAdd(out, local);
}

extern "C" void kernel_launch(void* const* d_in, const int* in_sizes, int n_in,
                              void* d_out, int out_size, void* d_ws, size_t ws_size,
                              hipStream_t stream) {
  const float* centers  = (const float*)d_in[0];
  const float* features = (const float*)d_in[1];
  const int*   targets  = (const int*)d_in[2];

  char* ws = (char*)d_ws;
  int*            cnt    = (int*)ws;
  float*          Eacc   = (float*)(ws + 512);
  float*          Sacc   = (float*)(ws + 33280);
  int*            tgtAll = (int*)(ws + 66048);
  float4*         tbl    = (float4*)(ws + 99328);
  unsigned short* fbB    = (unsigned short*)(ws + 232448);
  unsigned short* fbA    = (unsigned short*)(ws + 2362368);
  float* out = (float*)d_out;

  hipMemsetAsync(ws, 0, 66048, stream);          // cnt + Eacc + Sacc
  hipMemsetAsync(d_out, 0, sizeof(float), stream);
  tgt_count_kernel<<<(NJP + 255) / 256, 256, 0, stream>>>(targets, cnt, tgtAll);
  prep_kernel<<<(NJP * 32 + 255) / 256, 256, 0, stream>>>(centers, features, tgtAll, cnt,
                                                          fbB, fbA, tbl);
  bal_mfma<<<512, 256, 0, stream>>>(fbA, fbB, tbl, Eacc, Sacc);
  bal_final<<<TWOB / 64, 256, 0, stream>>>(fbA, fbB, tbl, Eacc, Sacc, out);
}